// Round 5
// baseline (859.464 us; speedup 1.0000x reference)
//
#include <hip/hip_runtime.h>

// ---------------------------------------------------------------------------
// Decoder layer (B=4, S=2048, D=1024, H=16, Dh=64, FF=4096), f32 in/out.
// Round 4: new GEMM — 256x128 tile, BK=64, 8 waves, double-buffered LDS,
// counted vmcnt (never drains mid-loop), bank-conflict-free XOR-swizzled
// ds_read_b128, setprio around MFMA, XCD-aware block swizzle, merged QKV.
// Flash attention (swapped-operand 32x32) unchanged from round 3.
// ---------------------------------------------------------------------------

typedef _Float16 f16;
typedef _Float16 f16x8 __attribute__((ext_vector_type(8)));
typedef _Float16 f16x4 __attribute__((ext_vector_type(4)));
typedef float f32x4 __attribute__((ext_vector_type(4)));
typedef float f32x16 __attribute__((ext_vector_type(16)));
typedef unsigned int u32;

#define AS1 __attribute__((address_space(1)))
#define AS3 __attribute__((address_space(3)))

constexpr int S_LEN = 2048;
constexpr int DM    = 1024;

// ---- static device arena (byte offsets) ----
constexpr long OFF_W   = 0;                // transposed weights f16 (32 MiB)
constexpr long OFF_XB  = 32L  << 20;       // current stream, f16 [8192,1024]
constexpr long OFF_ENC = 48L  << 20;       // encoder f16
constexpr long OFF_Q   = 64L  << 20;
constexpr long OFF_K   = 80L  << 20;
constexpr long OFF_V   = 96L  << 20;
constexpr long OFF_VT  = 112L << 20;       // V transposed per head [bh][64][S]
constexpr long OFF_AC  = 128L << 20;       // attention concat f16
constexpr long OFF_HID = 144L << 20;       // FF hidden f16 [8192,4096]
constexpr long OFF_F1  = 208L << 20;       // f32 [8192,1024]
constexpr long OFF_F2  = 240L << 20;       // f32
constexpr long OFF_F3  = 272L << 20;       // f32
constexpr long BUF_BYTES = 304L << 20;

__device__ alignas(4096) unsigned char g_buf[BUF_BYTES];

constexpr long WQ1T = OFF_W + (0L  << 20);
constexpr long WK1T = OFF_W + (2L  << 20);
constexpr long WV1T = OFF_W + (4L  << 20);
constexpr long WO1T = OFF_W + (6L  << 20);
constexpr long WQ2T = OFF_W + (8L  << 20);
constexpr long WK2T = OFF_W + (10L << 20);
constexpr long WV2T = OFF_W + (12L << 20);
constexpr long WO2T = OFF_W + (14L << 20);
constexpr long WF1T = OFF_W + (16L << 20);  // [4096][1024]
constexpr long WF2T = OFF_W + (24L << 20);  // [1024][4096]

// ---------------------------------------------------------------------------
__global__ __launch_bounds__(256) void cvt_f32_f16_k(const float* __restrict__ in, long outOff)
{
    f16* out = (f16*)(g_buf + outOff);
    long i = (long)blockIdx.x * 256 + threadIdx.x;
    float4 v = ((const float4*)in)[i];
    f16x4 h;
    h.x = (f16)v.x; h.y = (f16)v.y; h.z = (f16)v.z; h.w = (f16)v.w;
    *(f16x4*)(out + i * 4) = h;
}

// weight transpose + convert: W f32 [K,N] -> Wt f16 [N,K]
__global__ __launch_bounds__(256) void transw_k(const float* __restrict__ W, long outOff, int K, int N)
{
    __shared__ float t[32][33];
    f16* Wt = (f16*)(g_buf + outOff);
    int tx = threadIdx.x, ty = threadIdx.y;
    int c0 = blockIdx.x * 32, r0 = blockIdx.y * 32;
#pragma unroll
    for (int i = 0; i < 4; ++i)
        t[ty + 8*i][tx] = W[(long)(r0 + ty + 8*i) * N + c0 + tx];
    __syncthreads();
#pragma unroll
    for (int i = 0; i < 4; ++i)
        Wt[(long)(c0 + ty + 8*i) * K + r0 + tx] = (f16)t[tx][ty + 8*i];
}

// per-head V transpose: V f16 [b*S+s][h*64+d] -> Vt f16 [bh][d][s]
__global__ __launch_bounds__(256) void transv_k(long vOff, long vtOff)
{
    __shared__ f16 t[32][33];
    const f16* V = (const f16*)(g_buf + vOff);
    f16* Vt = (f16*)(g_buf + vtOff);
    int tx = threadIdx.x, ty = threadIdx.y;
    int bh = blockIdx.z; int b = bh >> 4, h = bh & 15;
    int s0 = blockIdx.x * 32, d0 = blockIdx.y * 32;
#pragma unroll
    for (int i = 0; i < 4; ++i)
        t[ty + 8*i][tx] = V[(long)(b * S_LEN + s0 + ty + 8*i) * DM + h * 64 + d0 + tx];
    __syncthreads();
#pragma unroll
    for (int i = 0; i < 4; ++i)
        Vt[((long)bh * 64 + d0 + ty + 8*i) * S_LEN + s0 + tx] = t[tx][ty + 8*i];
}

// ---------------------------------------------------------------------------
// GEMM v2: C[M,N] = A[M,K] @ Bt[N,K] (+bias / relu), BM=256 BN=128 BK=64.
// 8 waves (4M x 2N), per-wave 64x64. Double-buffered LDS, 2 phases per
// K-tile (phase = k-half of 32). Counted vmcnt(3): next-tile halves stay in
// flight across barriers. XOR block swizzle (b ^= (row>>1)&3) on both the
// staging source and the ds_read -> conflict-free b128 reads.
// Output addressing: idx = (c>>10)*chunkStride + r*ldc + (c&1023), bias from
// b[c>>10][c&1023] -> supports merged-QKV chunked outputs and plain layouts.
// MODE 0: f16 + bias   MODE 1: f16 + bias + relu   MODE 2: f32 + bias
// ---------------------------------------------------------------------------
template<int MODE>
__global__ __launch_bounds__(512) void gemm2_k(
    long aOff, long bOff, long cOff,
    const float* __restrict__ b0, const float* __restrict__ b1,
    const float* __restrict__ b2, const float* __restrict__ b3,
    int K, int lda, int ldb, int ldc, long chunkStride)
{
    __shared__ alignas(16) f16 As[2][2][256 * 32];   // [buf][khalf][row*32+k]
    __shared__ alignas(16) f16 Bs[2][2][128 * 32];

    const int tid  = threadIdx.x;
    const int lane = tid & 63;
    const int w    = tid >> 6;
    const int cB   = lane & 15;
    const int hi   = lane >> 4;

    // bijective XCD swizzle (all grids are multiples of 8 blocks)
    const int nwg = gridDim.x * gridDim.y;
    const int id  = blockIdx.y * gridDim.x + blockIdx.x;
    const int swz = (id & 7) * (nwg >> 3) + (id >> 3);
    const int bx  = swz % gridDim.x, by = swz / gridDim.x;
    const int row0 = by * 256, col0 = bx * 128;

    const f16* Ab = (const f16*)(g_buf + aOff);
    const f16* Bb = (const f16*)(g_buf + bOff);

    const int awr = (w >> 1) * 64;   // wave row base within tile
    const int bwc = (w & 1) * 64;    // wave col base within tile

    f32x4 acc[4][4] = {};

    // stage one k-half of tile kt into buf: A-half 16KB (l=0,1) + B-half 8KB (l=2)
    auto stage = [&](int buf, int kt, int p) {
        const int kB = kt * 64 + p * 32;
#pragma unroll
        for (int l = 0; l < 3; ++l) {
            const int s0 = l * 512 + w * 64;       // wave-uniform segment base
            const int s  = s0 + lane;
            if (l < 2) {
                const int srow = s >> 2, sb = s & 3;
                const int gk = (sb ^ ((srow >> 1) & 3)) << 3;
                const f16* gp = Ab + (long)(row0 + srow) * lda + kB + gk;
                __builtin_amdgcn_global_load_lds((const AS1 void*)gp,
                    (AS3 void*)(&As[buf][p][0] + s0 * 8), 16, 0, 0);
            } else {
                const int s2 = s - 1024;
                const int srow = s2 >> 2, sb = s2 & 3;
                const int gk = (sb ^ ((srow >> 1) & 3)) << 3;
                const f16* gp = Bb + (long)(col0 + srow) * ldb + kB + gk;
                __builtin_amdgcn_global_load_lds((const AS1 void*)gp,
                    (AS3 void*)(&Bs[buf][p][0] + (s0 - 1024) * 8), 16, 0, 0);
            }
        }
    };

    auto compute = [&](int buf, int p) {
        f16x8 af[4], bfr[4];
#pragma unroll
        for (int m = 0; m < 4; ++m) {
            const int row = awr + m * 16 + cB;
            af[m] = *(const f16x8*)&As[buf][p][row * 32 + ((hi ^ ((row >> 1) & 3)) << 3)];
        }
#pragma unroll
        for (int n = 0; n < 4; ++n) {
            const int row = bwc + n * 16 + cB;
            bfr[n] = *(const f16x8*)&Bs[buf][p][row * 32 + ((hi ^ ((row >> 1) & 3)) << 3)];
        }
        __builtin_amdgcn_s_setprio(1);
#pragma unroll
        for (int m = 0; m < 4; ++m)
#pragma unroll
            for (int n = 0; n < 4; ++n)
                acc[m][n] = __builtin_amdgcn_mfma_f32_16x16x32_f16(af[m], bfr[n], acc[m][n], 0, 0, 0);
        __builtin_amdgcn_s_setprio(0);
    };

    // prologue: tile 0, both halves
    stage(0, 0, 0);
    stage(0, 0, 1);

    const int nt = K >> 6;
    for (int t = 0; t < nt; ++t) {
        const int cur = t & 1;
        // ---- phase 0 (k-half 0) ----
        asm volatile("s_waitcnt vmcnt(3)" ::: "memory");
        __builtin_amdgcn_s_barrier();
        __builtin_amdgcn_sched_barrier(0);
        if (t + 1 < nt) stage(cur ^ 1, t + 1, 0);
        compute(cur, 0);
        // ---- phase 1 (k-half 1) ----
        if (t + 1 < nt) {
            asm volatile("s_waitcnt vmcnt(3)" ::: "memory");
            __builtin_amdgcn_s_barrier();
            __builtin_amdgcn_sched_barrier(0);
            stage(cur ^ 1, t + 1, 1);
        } else {
            asm volatile("s_waitcnt vmcnt(0)" ::: "memory");
            __builtin_amdgcn_s_barrier();
            __builtin_amdgcn_sched_barrier(0);
        }
        compute(cur, 1);
    }

    // ---- epilogue ----
    float* Cf = (float*)(g_buf + cOff);
    f16*  Ch = (f16*)(g_buf + cOff);
    const int ch = col0 >> 10;                       // chunk uniform per block
    const float* bp = (ch == 0) ? b0 : (ch == 1) ? b1 : (ch == 2) ? b2 : b3;
    const long cBase = (long)ch * chunkStride;
    const int rB = hi * 4;
#pragma unroll
    for (int m = 0; m < 4; ++m) {
#pragma unroll
        for (int n = 0; n < 4; ++n) {
            const int c = col0 + bwc + n * 16 + cB;
            const float bv = bp[c & 1023];
#pragma unroll
            for (int j = 0; j < 4; ++j) {
                const int r = row0 + awr + m * 16 + rB + j;
                float v = acc[m][n][j] + bv;
                if constexpr (MODE == 1) v = fmaxf(v, 0.f);
                const long idx = cBase + (long)r * ldc + (c & 1023);
                if constexpr (MODE == 2) Cf[idx] = v;
                else                     Ch[idx] = (f16)v;
            }
        }
    }
}

// ---------------------------------------------------------------------------
// Fused flash attention (round-3 structure, unchanged).
// ---------------------------------------------------------------------------
template<int CAUSAL>
__global__ __launch_bounds__(256, 3) void flash_k(long qOff, long kOff, long vtOff, long oOff)
{
    __shared__ alignas(16) f16 KV[2][2][4096];   // [buf][K/V][64*64]

    const int tid  = threadIdx.x;
    const int lane = tid & 63;
    const int w    = tid >> 6;
    const int ql   = lane & 31;
    const int s    = lane >> 5;
    const int qt   = CAUSAL ? (15 - (int)blockIdx.x) : (int)blockIdx.x;
    const int bh   = blockIdx.y;
    const int b = bh >> 4, h = bh & 15;
    const int q0 = qt * 128;
    const long tokB = (long)b * S_LEN;

    const f16* Qb  = (const f16*)(g_buf + qOff);
    const f16* Kb  = (const f16*)(g_buf + kOff);
    const f16* Vtb = (const f16*)(g_buf + vtOff) + (long)bh * 64 * S_LEN;
    f16* Ob = (f16*)(g_buf + oOff);

    const int r8 = lane >> 3;
    const int c8 = lane & 7;
    const int sb = c8 ^ r8;
    const int nch = CAUSAL ? 2 * (qt + 1) : (S_LEN / 64);

    auto stage = [&](int buf, int c) {
        const int kv0s = c * 64;
#pragma unroll
        for (int t = 0; t < 2; ++t) {
            const int grp = w * 2 + t;
            const int row = grp * 8 + r8;
            __builtin_amdgcn_global_load_lds(
                (const AS1 void*)(Kb + (tokB + kv0s + row) * DM + h * 64 + sb * 8),
                (AS3 void*)(&KV[buf][0][grp * 512]), 16, 0, 0);
            __builtin_amdgcn_global_load_lds(
                (const AS1 void*)(Vtb + (long)row * S_LEN + kv0s + sb * 8),
                (AS3 void*)(&KV[buf][1][grp * 512]), 16, 0, 0);
        }
    };

    stage(0, 0);

    f16x8 qf[4];
    {
        const f16 hs = (f16)(0.125f * 1.44269504088896f);
        const f16* qrow = Qb + (tokB + q0 + w * 32 + ql) * DM + h * 64 + s * 8;
#pragma unroll
        for (int kk = 0; kk < 4; ++kk) {
            qf[kk] = *(const f16x8*)(qrow + kk * 16);
#pragma unroll
            for (int i = 0; i < 8; ++i) qf[kk][i] = qf[kk][i] * hs;
        }
    }

    f32x16 oacc[2] = {};
    float mrow = -1e30f, lrow = 0.f;

    for (int c = 0; c < nch; ++c) {
        const int cur = c & 1;
        const int kv0 = c * 64;
        if (c + 1 < nch) {
            stage(cur ^ 1, c + 1);
            asm volatile("s_waitcnt vmcnt(4)" ::: "memory");
        } else {
            asm volatile("s_waitcnt vmcnt(0)" ::: "memory");
        }
        __builtin_amdgcn_s_barrier();
        __builtin_amdgcn_sched_barrier(0);

        const bool active = !CAUSAL || (kv0 <= q0 + w * 32 + 31);
        if (active) {
            f32x16 p[2] = {};
#pragma unroll
            for (int kk = 0; kk < 4; ++kk) {
                const int t16 = (kk * 2 + s) ^ (ql & 7);
                f16x8 kf0 = *(const f16x8*)((const char*)&KV[cur][0][0] + ql * 128 + t16 * 16);
                f16x8 kf1 = *(const f16x8*)((const char*)&KV[cur][0][0] + (32 + ql) * 128 + t16 * 16);
                p[0] = __builtin_amdgcn_mfma_f32_32x32x16_f16(kf0, qf[kk], p[0], 0, 0, 0);
                p[1] = __builtin_amdgcn_mfma_f32_32x32x16_f16(kf1, qf[kk], p[1], 0, 0, 0);
            }

            if (CAUSAL && (kv0 + 63 > q0 + w * 32)) {
                const int q = q0 + w * 32 + ql;
#pragma unroll
                for (int v = 0; v < 2; ++v)
#pragma unroll
                    for (int r = 0; r < 16; ++r) {
                        const int kv = kv0 + v * 32 + (r & 3) + 8 * (r >> 2) + 4 * s;
                        if (kv > q) p[v][r] = -1e30f;
                    }
            }

            float rmax = p[0][0];
#pragma unroll
            for (int r = 1; r < 16; ++r) rmax = fmaxf(rmax, p[0][r]);
#pragma unroll
            for (int r = 0; r < 16; ++r) rmax = fmaxf(rmax, p[1][r]);
            rmax = fmaxf(rmax, __shfl_xor(rmax, 32));

            if (!__all(rmax <= mrow + 8.0f)) {
                const float mn = fmaxf(mrow, rmax);
                const float alpha = __builtin_amdgcn_exp2f(mrow - mn);
                lrow *= alpha;
                mrow = mn;
#pragma unroll
                for (int r = 0; r < 16; ++r) {
                    const int qr = (r & 3) + 8 * (r >> 2) + 4 * s;
                    const float ab = __shfl(alpha, qr);
                    oacc[0][r] *= ab;
                    oacc[1][r] *= ab;
                }
            }

            float rsum = 0.f;
#pragma unroll
            for (int v = 0; v < 2; ++v)
#pragma unroll
                for (int r = 0; r < 16; ++r) {
                    const float pe = __builtin_amdgcn_exp2f(p[v][r] - mrow);
                    p[v][r] = pe;
                    rsum += pe;
                }
            rsum += __shfl_xor(rsum, 32);
            lrow += rsum;

            u32 pk[2][4][2];
#pragma unroll
            for (int v = 0; v < 2; ++v)
#pragma unroll
                for (int a = 0; a < 4; ++a)
#pragma unroll
                    for (int cc = 0; cc < 2; ++cc) {
                        union { f16 hh[2]; u32 u; } t;
                        t.hh[0] = (f16)p[v][4 * a + 2 * cc];
                        t.hh[1] = (f16)p[v][4 * a + 2 * cc + 1];
                        pk[v][a][cc] = t.u;
                    }
            u32 loc[2][2][2], exv[2][2][2];
#pragma unroll
            for (int v = 0; v < 2; ++v)
#pragma unroll
                for (int k1 = 0; k1 < 2; ++k1)
#pragma unroll
                    for (int cc = 0; cc < 2; ++cc) {
                        const u32 pe = pk[v][2 * k1][cc];
                        const u32 po = pk[v][2 * k1 + 1][cc];
                        loc[v][k1][cc] = s ? po : pe;
                        const u32 snd = s ? pe : po;
                        exv[v][k1][cc] = (u32)__shfl_xor((int)snd, 32);
                    }

#pragma unroll
            for (int ks = 0; ks < 4; ++ks) {
                const int v = ks >> 1, k1 = ks & 1;
                union { u32 u[4]; f16x8 hv; } pa;
                pa.u[0] = s ? exv[v][k1][0] : loc[v][k1][0];
                pa.u[1] = s ? exv[v][k1][1] : loc[v][k1][1];
                pa.u[2] = s ? loc[v][k1][0] : exv[v][k1][0];
                pa.u[3] = s ? loc[v][k1][1] : exv[v][k1][1];
                const int tv = (ks * 2 + s) ^ (ql & 7);
                f16x8 vf0 = *(const f16x8*)((const char*)&KV[cur][1][0] + ql * 128 + tv * 16);
                f16x8 vf1 = *(const f16x8*)((const char*)&KV[cur][1][0] + (32 + ql) * 128 + tv * 16);
                oacc[0] = __builtin_amdgcn_mfma_f32_32x32x16_f16(pa.hv, vf0, oacc[0], 0, 0, 0);
                oacc[1] = __builtin_amdgcn_mfma_f32_32x32x16_f16(pa.hv, vf1, oacc[1], 0, 0, 0);
            }
        }
        asm volatile("s_waitcnt lgkmcnt(0)" ::: "memory");
        __builtin_amdgcn_sched_barrier(0);
        __builtin_amdgcn_s_barrier();
        __builtin_amdgcn_sched_barrier(0);
    }

    f16* Es = ((f16*)&KV[0][0][0]) + w * 2304;
    const float linv = 1.0f / lrow;
#pragma unroll
    for (int r = 0; r < 16; ++r) {
        const int qr = (r & 3) + 8 * (r >> 2) + 4 * s;
        const float lb = __shfl(linv, qr);
        Es[qr * 72 + ql]      = (f16)(oacc[0][r] * lb);
        Es[qr * 72 + 32 + ql] = (f16)(oacc[1][r] * lb);
    }
    const int orow = lane >> 1;
    const int oh   = (lane & 1) * 32;
    const f16* srcp = ((const f16*)&KV[0][0][0]) + w * 2304 + orow * 72 + oh;
    f16* dst = Ob + (tokB + q0 + w * 32 + orow) * DM + h * 64 + oh;
#pragma unroll
    for (int t = 0; t < 4; ++t)
        *(f16x8*)(dst + t * 8) = *(const f16x8*)(srcp + t * 8);
}

// ---------------------------------------------------------------------------
// fused residual-add + LayerNorm
// ---------------------------------------------------------------------------
__global__ __launch_bounds__(256) void ln_k(
    long inOff, const float* __restrict__ residExt, long residOff,
    const float* __restrict__ gamma, const float* __restrict__ beta,
    float* __restrict__ outFExt, long outFOff, long outHOff)
{
    const float* in    = (const float*)(g_buf + inOff);
    const float* resid = residExt ? residExt : (const float*)(g_buf + residOff);
    float* outF = outFExt ? outFExt : (float*)(g_buf + outFOff);
    f16*  outH = (f16*)(g_buf + outHOff);

    const long row = blockIdx.x;
    const int tid = threadIdx.x;
    const int lane = tid & 63, wid = tid >> 6;

    float4 a  = ((const float4*)(in    + row * DM))[tid];
    float4 rr = ((const float4*)(resid + row * DM))[tid];
    float x0 = a.x + rr.x, x1 = a.y + rr.y, x2 = a.z + rr.z, x3 = a.w + rr.w;

    __shared__ float red[4];
    float ss = x0 + x1 + x2 + x3;
#pragma unroll
    for (int o = 32; o > 0; o >>= 1) ss += __shfl_xor(ss, o);
    if (lane == 0) red[wid] = ss;
    __syncthreads();
    const float mu = (red[0] + red[1] + red[2] + red[3]) * (1.0f / DM);

    float d0 = x0 - mu, d1 = x1 - mu, d2 = x2 - mu, d3 = x3 - mu;
    float qq = d0*d0 + d1*d1 + d2*d2 + d3*d3;
#pragma unroll
    for (int o = 32; o > 0; o >>= 1) qq += __shfl_xor(qq, o);
    __syncthreads();
    if (lane == 0) red[wid] = qq;
    __syncthreads();
    const float var = (red[0] + red[1] + red[2] + red[3]) * (1.0f / DM);
    const float rs = rsqrtf(var + 1e-6f);

    float4 g  = ((const float4*)gamma)[tid];
    float4 be = ((const float4*)beta)[tid];
    float y0 = d0 * rs * g.x + be.x;
    float y1 = d1 * rs * g.y + be.y;
    float y2 = d2 * rs * g.z + be.z;
    float y3 = d3 * rs * g.w + be.w;

    ((float4*)(outF + row * DM))[tid] = make_float4(y0, y1, y2, y3);
    f16x4 hh; hh.x = (f16)y0; hh.y = (f16)y1; hh.z = (f16)y2; hh.w = (f16)y3;
    *(f16x4*)(outH + row * DM + tid * 4) = hh;
}

// ---------------------------------------------------------------------------
extern "C" void kernel_launch(void* const* d_in, const int* in_sizes, int n_in,
                              void* d_out, int out_size, void* d_ws, size_t ws_size,
                              hipStream_t stream)
{
    (void)in_sizes; (void)n_in; (void)d_ws; (void)ws_size; (void)out_size;
    const float* x   = (const float*)d_in[0];
    const float* enc = (const float*)d_in[1];
    const float* wq1 = (const float*)d_in[2];  const float* bq1 = (const float*)d_in[3];
    const float* wk1 = (const float*)d_in[4];  const float* bk1 = (const float*)d_in[5];
    const float* wv1 = (const float*)d_in[6];  const float* bv1 = (const float*)d_in[7];
    const float* wo1 = (const float*)d_in[8];  const float* bo1 = (const float*)d_in[9];
    const float* wq2 = (const float*)d_in[10]; const float* bq2 = (const float*)d_in[11];
    const float* wk2 = (const float*)d_in[12]; const float* bk2 = (const float*)d_in[13];
    const float* wv2 = (const float*)d_in[14]; const float* bv2 = (const float*)d_in[15];
    const float* wo2 = (const float*)d_in[16]; const float* bo2 = (const float*)d_in[17];
    const float* wf1 = (const float*)d_in[18]; const float* bf1 = (const float*)d_in[19];
    const float* wf2 = (const float*)d_in[20]; const float* bf2 = (const float*)d_in[21];
    const float* g1  = (const float*)d_in[22]; const float* be1 = (const float*)d_in[23];
    const float* g2  = (const float*)d_in[24]; const float* be2 = (const float*)d_in[25];
    const float* g3  = (const float*)d_in[26]; const float* be3 = (const float*)d_in[27];
    float* out = (float*)d_out;

    const dim3 T256(256), T512(512), T32x8(32, 8);
    const long QKV_CHUNK = 8192L * 1024;   // elements between OFF_Q / OFF_K / OFF_V

    // ---- converts & weight transposes ----
    cvt_f32_f16_k<<<8192, T256, 0, stream>>>(x,   OFF_XB);
    cvt_f32_f16_k<<<8192, T256, 0, stream>>>(enc, OFF_ENC);
    transw_k<<<dim3(32, 32),  T32x8, 0, stream>>>(wq1, WQ1T, 1024, 1024);
    transw_k<<<dim3(32, 32),  T32x8, 0, stream>>>(wk1, WK1T, 1024, 1024);
    transw_k<<<dim3(32, 32),  T32x8, 0, stream>>>(wv1, WV1T, 1024, 1024);
    transw_k<<<dim3(32, 32),  T32x8, 0, stream>>>(wo1, WO1T, 1024, 1024);
    transw_k<<<dim3(32, 32),  T32x8, 0, stream>>>(wq2, WQ2T, 1024, 1024);
    transw_k<<<dim3(32, 32),  T32x8, 0, stream>>>(wk2, WK2T, 1024, 1024);
    transw_k<<<dim3(32, 32),  T32x8, 0, stream>>>(wv2, WV2T, 1024, 1024);
    transw_k<<<dim3(32, 32),  T32x8, 0, stream>>>(wo2, WO2T, 1024, 1024);
    transw_k<<<dim3(128, 32), T32x8, 0, stream>>>(wf1, WF1T, 1024, 4096);
    transw_k<<<dim3(32, 128), T32x8, 0, stream>>>(wf2, WF2T, 4096, 1024);

    // ---- masked self-attention ----
    // merged QKV projection: Bt rows 0..3071 = [WQ1T|WK1T|WV1T] (contiguous)
    gemm2_k<0><<<dim3(24, 32), T512, 0, stream>>>(OFF_XB, WQ1T, OFF_Q,
        bq1, bk1, bv1, bv1, 1024, 1024, 1024, 1024, QKV_CHUNK);
    transv_k<<<dim3(64, 2, 64), T32x8, 0, stream>>>(OFF_V, OFF_VT);
    flash_k<1><<<dim3(16, 64), T256, 0, stream>>>(OFF_Q, OFF_K, OFF_VT, OFF_AC);
    gemm2_k<2><<<dim3(8, 32), T512, 0, stream>>>(OFF_AC, WO1T, OFF_F2,
        bo1, bo1, bo1, bo1, 1024, 1024, 1024, 1024, 1024);
    ln_k<<<8192, T256, 0, stream>>>(OFF_F2, x, 0, g1, be1, nullptr, OFF_F1, OFF_XB);

    // ---- cross-attention (q=enc, k=enc, v=x1) ----
    gemm2_k<0><<<dim3(16, 32), T512, 0, stream>>>(OFF_ENC, WQ2T, OFF_Q,
        bq2, bk2, bk2, bk2, 1024, 1024, 1024, 1024, QKV_CHUNK);
    gemm2_k<0><<<dim3(8, 32), T512, 0, stream>>>(OFF_XB, WV2T, OFF_V,
        bv2, bv2, bv2, bv2, 1024, 1024, 1024, 1024, 1024);
    transv_k<<<dim3(64, 2, 64), T32x8, 0, stream>>>(OFF_V, OFF_VT);
    flash_k<0><<<dim3(16, 64), T256, 0, stream>>>(OFF_Q, OFF_K, OFF_VT, OFF_AC);
    gemm2_k<2><<<dim3(8, 32), T512, 0, stream>>>(OFF_AC, WO2T, OFF_F2,
        bo2, bo2, bo2, bo2, 1024, 1024, 1024, 1024, 1024);
    ln_k<<<8192, T256, 0, stream>>>(OFF_F2, nullptr, OFF_F1, g2, be2, nullptr, OFF_F3, OFF_XB);

    // ---- feed-forward ----
    gemm2_k<1><<<dim3(32, 32), T512, 0, stream>>>(OFF_XB, WF1T, OFF_HID,
        bf1, bf1 + 1024, bf1 + 2048, bf1 + 3072, 1024, 1024, 1024, 4096, 1024);
    gemm2_k<2><<<dim3(8, 32), T512, 0, stream>>>(OFF_HID, WF2T, OFF_F2,
        bf2, bf2, bf2, bf2, 4096, 4096, 4096, 1024, 1024);
    ln_k<<<8192, T256, 0, stream>>>(OFF_F2, nullptr, OFF_F3, g3, be3, out, 0, OFF_XB);
}

// Round 6
// 720.110 us; speedup vs baseline: 1.1935x; 1.1935x over previous
//
#include <hip/hip_runtime.h>

// ---------------------------------------------------------------------------
// Decoder layer (B=4, S=2048, D=1024, H=16, Dh=64, FF=4096), f32 in/out.
// Round 6: GEMM v3 — 128x128 tile, BK=32, 4 waves, TRIPLE-buffered LDS
// (48KB -> 3 blocks/CU), prefetch depth 2, counted vmcnt(4), one barrier
// per K-tile, conflict-free XOR swizzle, XCD swizzle. V-transpose fused
// into V-projection epilogue; cvt and weight transposes merged.
// Flash attention (swapped-operand 32x32) unchanged.
// ---------------------------------------------------------------------------

typedef _Float16 f16;
typedef _Float16 f16x8 __attribute__((ext_vector_type(8)));
typedef _Float16 f16x4 __attribute__((ext_vector_type(4)));
typedef float f32x4 __attribute__((ext_vector_type(4)));
typedef float f32x16 __attribute__((ext_vector_type(16)));
typedef unsigned int u32;

#define AS1 __attribute__((address_space(1)))
#define AS3 __attribute__((address_space(3)))

constexpr int S_LEN = 2048;
constexpr int DM    = 1024;

// ---- static device arena (byte offsets) ----
constexpr long OFF_W   = 0;                // transposed weights f16 (32 MiB)
constexpr long OFF_XB  = 32L  << 20;       // current stream, f16 [8192,1024]
constexpr long OFF_ENC = 48L  << 20;       // encoder f16
constexpr long OFF_Q   = 64L  << 20;
constexpr long OFF_K   = 80L  << 20;
constexpr long OFF_V   = 96L  << 20;       // (unused scratch)
constexpr long OFF_VT  = 112L << 20;       // V transposed per head [bh][64][S]
constexpr long OFF_AC  = 128L << 20;       // attention concat f16
constexpr long OFF_HID = 144L << 20;       // FF hidden f16 [8192,4096]
constexpr long OFF_F1  = 208L << 20;       // f32 [8192,1024]
constexpr long OFF_F2  = 240L << 20;       // f32
constexpr long OFF_F3  = 272L << 20;       // f32
constexpr long BUF_BYTES = 304L << 20;

__device__ alignas(4096) unsigned char g_buf[BUF_BYTES];

constexpr long WQ1T = OFF_W + (0L  << 20);
constexpr long WF1T = OFF_W + (16L << 20);  // [4096][1024]
constexpr long WF2T = OFF_W + (24L << 20);  // [1024][4096]
constexpr long WO1T = OFF_W + (6L  << 20);
constexpr long WQ2T = OFF_W + (8L  << 20);
constexpr long WV2T = OFF_W + (12L << 20);
constexpr long WO2T = OFF_W + (14L << 20);

// ---------------------------------------------------------------------------
// merged f32 -> f16 convert for x and enc (single launch)
// ---------------------------------------------------------------------------
__global__ __launch_bounds__(256) void cvt2_k(const float* __restrict__ x,
                                              const float* __restrict__ enc)
{
    const int bid = blockIdx.x;
    const bool second = bid >= 8192;
    const float* in = second ? enc : x;
    f16* out = (f16*)(g_buf + (second ? OFF_ENC : OFF_XB));
    long i = (long)(second ? bid - 8192 : bid) * 256 + threadIdx.x;
    float4 v = ((const float4*)in)[i];
    f16x4 h;
    h.x = (f16)v.x; h.y = (f16)v.y; h.z = (f16)v.z; h.w = (f16)v.w;
    *(f16x4*)(out + i * 4) = h;
}

// ---------------------------------------------------------------------------
// merged weight transpose+convert: all 10 weights in one launch.
// job 0..7: 1024x1024 -> 2MB apart from WQ1T; job 8: wf1; job 9: wf2.
// ---------------------------------------------------------------------------
struct TWJobs { const float* src[10]; };

__global__ __launch_bounds__(256) void transw_all_k(TWJobs jobs)
{
    __shared__ float t[32][33];
    const int bid = blockIdx.x;
    int j, local;
    if (bid < 8192)       { j = bid >> 10; local = bid & 1023; }
    else if (bid < 12288) { j = 8; local = bid - 8192; }
    else                  { j = 9; local = bid - 12288; }
    const int K = (j == 9) ? 4096 : 1024;
    const int N = (j == 8) ? 4096 : 1024;
    const int tnx = N >> 5;
    const int tx32 = local % tnx, ty32 = local / tnx;
    const long dstOff = (j < 8) ? (long)j * (2L << 20) : ((j == 8) ? WF1T : WF2T);
    const float* W = jobs.src[j];
    f16* Wt = (f16*)(g_buf + dstOff);

    int tx = threadIdx.x, ty = threadIdx.y;
    int c0 = tx32 * 32, r0 = ty32 * 32;
#pragma unroll
    for (int i = 0; i < 4; ++i)
        t[ty + 8*i][tx] = W[(long)(r0 + ty + 8*i) * N + c0 + tx];
    __syncthreads();
#pragma unroll
    for (int i = 0; i < 4; ++i)
        Wt[(long)(c0 + ty + 8*i) * K + r0 + tx] = (f16)t[tx][ty + 8*i];
}

// ---------------------------------------------------------------------------
// GEMM v3: C[M,N] = A[M,K] @ Bt[N,K] (+bias / relu), BM=BN=128, BK=32.
// 4 waves (2x2, 64x64/wave). Triple-buffered LDS (48KB -> 3 blocks/CU),
// prefetch depth 2, counted vmcnt(4) (vmcnt(0) only on the last tile),
// one raw barrier per K-tile. XOR-swizzled staging source + ds_read
// (conflict-free). Bijective XCD block swizzle.
// Epilogue chunking: ch = col0>>10; idx = ch*chunkStride + r*ldc + (c&1023);
// bias = b[ch][c&1023]. If ch==tvch the chunk is written TRANSPOSED per-head
// into Vt[bh][d][s] (fused V transpose).
// MODE 0: f16 + bias   MODE 1: f16 + bias + relu   MODE 2: f32 + bias
// ---------------------------------------------------------------------------
template<int MODE>
__global__ __launch_bounds__(256) void gemm3_k(
    long aOff, long bOff, long cOff, long vtOff,
    const float* __restrict__ b0, const float* __restrict__ b1,
    const float* __restrict__ b2, const float* __restrict__ b3,
    int K, int lda, int ldb, int ldc, long chunkStride, int tvch)
{
    __shared__ alignas(16) f16 As[3][128 * 32];
    __shared__ alignas(16) f16 Bs[3][128 * 32];

    const int tid  = threadIdx.x;
    const int lane = tid & 63;
    const int w    = tid >> 6;
    const int cB   = lane & 15;
    const int hi   = lane >> 4;

    // bijective XCD swizzle (all grids are multiples of 8 blocks)
    const int nwg = gridDim.x * gridDim.y;
    const int id  = blockIdx.y * gridDim.x + blockIdx.x;
    const int swz = (id & 7) * (nwg >> 3) + (id >> 3);
    const int bx  = swz % gridDim.x, by = swz / gridDim.x;
    const int row0 = by * 128, col0 = bx * 128;

    const f16* Ab = (const f16*)(g_buf + aOff);
    const f16* Bb = (const f16*)(g_buf + bOff);

    const int wr = (w >> 1) * 64;
    const int wc = (w & 1) * 64;

    f32x4 acc[4][4] = {};

    // stage tile kt into buf: A 8KB + B 8KB, 4 loads/thread, swizzled source
    auto stage = [&](int buf, int kt) {
        const int kB = kt * 32;
        const int base = w * 64;
#pragma unroll
        for (int r = 0; r < 2; ++r) {
            const int idx  = r * 256 + base + lane;
            const int srow = idx >> 2, sb = idx & 3;
            const int gk = (sb ^ ((srow >> 1) & 3)) << 3;
            __builtin_amdgcn_global_load_lds(
                (const AS1 void*)(Ab + (long)(row0 + srow) * lda + kB + gk),
                (AS3 void*)(&As[buf][(r * 256 + base) * 8]), 16, 0, 0);
            __builtin_amdgcn_global_load_lds(
                (const AS1 void*)(Bb + (long)(col0 + srow) * ldb + kB + gk),
                (AS3 void*)(&Bs[buf][(r * 256 + base) * 8]), 16, 0, 0);
        }
    };

    const int nt = K >> 5;
    stage(0, 0);
    stage(1, 1);          // 8 loads outstanding per thread

    for (int t = 0; t < nt; ++t) {
        if (nt - t >= 2) asm volatile("s_waitcnt vmcnt(4)" ::: "memory");
        else             asm volatile("s_waitcnt vmcnt(0)" ::: "memory");
        __builtin_amdgcn_s_barrier();
        __builtin_amdgcn_sched_barrier(0);
        if (t + 2 < nt) stage((t + 2) % 3, t + 2);

        const int cur = t % 3;
        f16x8 af[4], bf[4];
#pragma unroll
        for (int m = 0; m < 4; ++m) {
            const int row = wr + m * 16 + cB;
            af[m] = *(const f16x8*)&As[cur][row * 32 + ((hi ^ ((row >> 1) & 3)) << 3)];
        }
#pragma unroll
        for (int n = 0; n < 4; ++n) {
            const int row = wc + n * 16 + cB;
            bf[n] = *(const f16x8*)&Bs[cur][row * 32 + ((hi ^ ((row >> 1) & 3)) << 3)];
        }
#pragma unroll
        for (int m = 0; m < 4; ++m)
#pragma unroll
            for (int n = 0; n < 4; ++n)
                acc[m][n] = __builtin_amdgcn_mfma_f32_16x16x32_f16(af[m], bf[n], acc[m][n], 0, 0, 0);
    }

    // ---- epilogue ----
    const int ch = col0 >> 10;
    const float* bp = (ch == 0) ? b0 : (ch == 1) ? b1 : (ch == 2) ? b2 : b3;

    if (MODE == 0 && ch == tvch) {
        // fused per-head V transpose: Vt[bh][d][s]
        f16* Vt = (f16*)(g_buf + vtOff);
#pragma unroll
        for (int m = 0; m < 4; ++m) {
#pragma unroll
            for (int n = 0; n < 4; ++n) {
                const int c = col0 + wc + n * 16 + cB;
                const int hh = (c >> 6) & 15, dd = c & 63;
                const float bv = bp[c & 1023];
                const int r0e = row0 + wr + m * 16 + hi * 4;
                const int bb = r0e >> 11, sS = r0e & 2047;
                f16x4 hv;
#pragma unroll
                for (int jj = 0; jj < 4; ++jj) hv[jj] = (f16)(acc[m][n][jj] + bv);
                *(f16x4*)(Vt + (((long)(bb * 16 + hh) * 64 + dd) * 2048 + sS)) = hv;
            }
        }
        return;
    }

    float* Cf = (float*)(g_buf + cOff);
    f16*  Ch = (f16*)(g_buf + cOff);
    const long cBase = (long)ch * chunkStride;
#pragma unroll
    for (int m = 0; m < 4; ++m) {
#pragma unroll
        for (int n = 0; n < 4; ++n) {
            const int c = col0 + wc + n * 16 + cB;
            const float bv = bp[c & 1023];
#pragma unroll
            for (int jj = 0; jj < 4; ++jj) {
                const int r = row0 + wr + m * 16 + hi * 4 + jj;
                float v = acc[m][n][jj] + bv;
                if constexpr (MODE == 1) v = fmaxf(v, 0.f);
                const long idx = cBase + (long)r * ldc + (c & 1023);
                if constexpr (MODE == 2) Cf[idx] = v;
                else                     Ch[idx] = (f16)v;
            }
        }
    }
}

// ---------------------------------------------------------------------------
// Fused flash attention (round-3 structure, unchanged).
// ---------------------------------------------------------------------------
template<int CAUSAL>
__global__ __launch_bounds__(256, 3) void flash_k(long qOff, long kOff, long vtOff, long oOff)
{
    __shared__ alignas(16) f16 KV[2][2][4096];   // [buf][K/V][64*64]

    const int tid  = threadIdx.x;
    const int lane = tid & 63;
    const int w    = tid >> 6;
    const int ql   = lane & 31;
    const int s    = lane >> 5;
    const int qt   = CAUSAL ? (15 - (int)blockIdx.x) : (int)blockIdx.x;
    const int bh   = blockIdx.y;
    const int b = bh >> 4, h = bh & 15;
    const int q0 = qt * 128;
    const long tokB = (long)b * S_LEN;

    const f16* Qb  = (const f16*)(g_buf + qOff);
    const f16* Kb  = (const f16*)(g_buf + kOff);
    const f16* Vtb = (const f16*)(g_buf + vtOff) + (long)bh * 64 * S_LEN;
    f16* Ob = (f16*)(g_buf + oOff);

    const int r8 = lane >> 3;
    const int c8 = lane & 7;
    const int sb = c8 ^ r8;
    const int nch = CAUSAL ? 2 * (qt + 1) : (S_LEN / 64);

    auto stage = [&](int buf, int c) {
        const int kv0s = c * 64;
#pragma unroll
        for (int t = 0; t < 2; ++t) {
            const int grp = w * 2 + t;
            const int row = grp * 8 + r8;
            __builtin_amdgcn_global_load_lds(
                (const AS1 void*)(Kb + (tokB + kv0s + row) * DM + h * 64 + sb * 8),
                (AS3 void*)(&KV[buf][0][grp * 512]), 16, 0, 0);
            __builtin_amdgcn_global_load_lds(
                (const AS1 void*)(Vtb + (long)row * S_LEN + kv0s + sb * 8),
                (AS3 void*)(&KV[buf][1][grp * 512]), 16, 0, 0);
        }
    };

    stage(0, 0);

    f16x8 qf[4];
    {
        const f16 hs = (f16)(0.125f * 1.44269504088896f);
        const f16* qrow = Qb + (tokB + q0 + w * 32 + ql) * DM + h * 64 + s * 8;
#pragma unroll
        for (int kk = 0; kk < 4; ++kk) {
            qf[kk] = *(const f16x8*)(qrow + kk * 16);
#pragma unroll
            for (int i = 0; i < 8; ++i) qf[kk][i] = qf[kk][i] * hs;
        }
    }

    f32x16 oacc[2] = {};
    float mrow = -1e30f, lrow = 0.f;

    for (int c = 0; c < nch; ++c) {
        const int cur = c & 1;
        const int kv0 = c * 64;
        if (c + 1 < nch) {
            stage(cur ^ 1, c + 1);
            asm volatile("s_waitcnt vmcnt(4)" ::: "memory");
        } else {
            asm volatile("s_waitcnt vmcnt(0)" ::: "memory");
        }
        __builtin_amdgcn_s_barrier();
        __builtin_amdgcn_sched_barrier(0);

        const bool active = !CAUSAL || (kv0 <= q0 + w * 32 + 31);
        if (active) {
            f32x16 p[2] = {};
#pragma unroll
            for (int kk = 0; kk < 4; ++kk) {
                const int t16 = (kk * 2 + s) ^ (ql & 7);
                f16x8 kf0 = *(const f16x8*)((const char*)&KV[cur][0][0] + ql * 128 + t16 * 16);
                f16x8 kf1 = *(const f16x8*)((const char*)&KV[cur][0][0] + (32 + ql) * 128 + t16 * 16);
                p[0] = __builtin_amdgcn_mfma_f32_32x32x16_f16(kf0, qf[kk], p[0], 0, 0, 0);
                p[1] = __builtin_amdgcn_mfma_f32_32x32x16_f16(kf1, qf[kk], p[1], 0, 0, 0);
            }

            if (CAUSAL && (kv0 + 63 > q0 + w * 32)) {
                const int q = q0 + w * 32 + ql;
#pragma unroll
                for (int v = 0; v < 2; ++v)
#pragma unroll
                    for (int r = 0; r < 16; ++r) {
                        const int kv = kv0 + v * 32 + (r & 3) + 8 * (r >> 2) + 4 * s;
                        if (kv > q) p[v][r] = -1e30f;
                    }
            }

            float rmax = p[0][0];
#pragma unroll
            for (int r = 1; r < 16; ++r) rmax = fmaxf(rmax, p[0][r]);
#pragma unroll
            for (int r = 0; r < 16; ++r) rmax = fmaxf(rmax, p[1][r]);
            rmax = fmaxf(rmax, __shfl_xor(rmax, 32));

            if (!__all(rmax <= mrow + 8.0f)) {
                const float mn = fmaxf(mrow, rmax);
                const float alpha = __builtin_amdgcn_exp2f(mrow - mn);
                lrow *= alpha;
                mrow = mn;
#pragma unroll
                for (int r = 0; r < 16; ++r) {
                    const int qr = (r & 3) + 8 * (r >> 2) + 4 * s;
                    const float ab = __shfl(alpha, qr);
                    oacc[0][r] *= ab;
                    oacc[1][r] *= ab;
                }
            }

            float rsum = 0.f;
#pragma unroll
            for (int v = 0; v < 2; ++v)
#pragma unroll
                for (int r = 0; r < 16; ++r) {
                    const float pe = __builtin_amdgcn_exp2f(p[v][r] - mrow);
                    p[v][r] = pe;
                    rsum += pe;
                }
            rsum += __shfl_xor(rsum, 32);
            lrow += rsum;

            u32 pk[2][4][2];
#pragma unroll
            for (int v = 0; v < 2; ++v)
#pragma unroll
                for (int a = 0; a < 4; ++a)
#pragma unroll
                    for (int cc = 0; cc < 2; ++cc) {
                        union { f16 hh[2]; u32 u; } t;
                        t.hh[0] = (f16)p[v][4 * a + 2 * cc];
                        t.hh[1] = (f16)p[v][4 * a + 2 * cc + 1];
                        pk[v][a][cc] = t.u;
                    }
            u32 loc[2][2][2], exv[2][2][2];
#pragma unroll
            for (int v = 0; v < 2; ++v)
#pragma unroll
                for (int k1 = 0; k1 < 2; ++k1)
#pragma unroll
                    for (int cc = 0; cc < 2; ++cc) {
                        const u32 pe = pk[v][2 * k1][cc];
                        const u32 po = pk[v][2 * k1 + 1][cc];
                        loc[v][k1][cc] = s ? po : pe;
                        const u32 snd = s ? pe : po;
                        exv[v][k1][cc] = (u32)__shfl_xor((int)snd, 32);
                    }

#pragma unroll
            for (int ks = 0; ks < 4; ++ks) {
                const int v = ks >> 1, k1 = ks & 1;
                union { u32 u[4]; f16x8 hv; } pa;
                pa.u[0] = s ? exv[v][k1][0] : loc[v][k1][0];
                pa.u[1] = s ? exv[v][k1][1] : loc[v][k1][1];
                pa.u[2] = s ? loc[v][k1][0] : exv[v][k1][0];
                pa.u[3] = s ? loc[v][k1][1] : exv[v][k1][1];
                const int tv = (ks * 2 + s) ^ (ql & 7);
                f16x8 vf0 = *(const f16x8*)((const char*)&KV[cur][1][0] + ql * 128 + tv * 16);
                f16x8 vf1 = *(const f16x8*)((const char*)&KV[cur][1][0] + (32 + ql) * 128 + tv * 16);
                oacc[0] = __builtin_amdgcn_mfma_f32_32x32x16_f16(pa.hv, vf0, oacc[0], 0, 0, 0);
                oacc[1] = __builtin_amdgcn_mfma_f32_32x32x16_f16(pa.hv, vf1, oacc[1], 0, 0, 0);
            }
        }
        asm volatile("s_waitcnt lgkmcnt(0)" ::: "memory");
        __builtin_amdgcn_sched_barrier(0);
        __builtin_amdgcn_s_barrier();
        __builtin_amdgcn_sched_barrier(0);
    }

    f16* Es = ((f16*)&KV[0][0][0]) + w * 2304;
    const float linv = 1.0f / lrow;
#pragma unroll
    for (int r = 0; r < 16; ++r) {
        const int qr = (r & 3) + 8 * (r >> 2) + 4 * s;
        const float lb = __shfl(linv, qr);
        Es[qr * 72 + ql]      = (f16)(oacc[0][r] * lb);
        Es[qr * 72 + 32 + ql] = (f16)(oacc[1][r] * lb);
    }
    const int orow = lane >> 1;
    const int oh   = (lane & 1) * 32;
    const f16* srcp = ((const f16*)&KV[0][0][0]) + w * 2304 + orow * 72 + oh;
    f16* dst = Ob + (tokB + q0 + w * 32 + orow) * DM + h * 64 + oh;
#pragma unroll
    for (int t = 0; t < 4; ++t)
        *(f16x8*)(dst + t * 8) = *(const f16x8*)(srcp + t * 8);
}

// ---------------------------------------------------------------------------
// fused residual-add + LayerNorm
// ---------------------------------------------------------------------------
__global__ __launch_bounds__(256) void ln_k(
    long inOff, const float* __restrict__ residExt, long residOff,
    const float* __restrict__ gamma, const float* __restrict__ beta,
    float* __restrict__ outFExt, long outFOff, long outHOff)
{
    const float* in    = (const float*)(g_buf + inOff);
    const float* resid = residExt ? residExt : (const float*)(g_buf + residOff);
    float* outF = outFExt ? outFExt : (float*)(g_buf + outFOff);
    f16*  outH = (f16*)(g_buf + outHOff);

    const long row = blockIdx.x;
    const int tid = threadIdx.x;
    const int lane = tid & 63, wid = tid >> 6;

    float4 a  = ((const float4*)(in    + row * DM))[tid];
    float4 rr = ((const float4*)(resid + row * DM))[tid];
    float x0 = a.x + rr.x, x1 = a.y + rr.y, x2 = a.z + rr.z, x3 = a.w + rr.w;

    __shared__ float red[4];
    float ss = x0 + x1 + x2 + x3;
#pragma unroll
    for (int o = 32; o > 0; o >>= 1) ss += __shfl_xor(ss, o);
    if (lane == 0) red[wid] = ss;
    __syncthreads();
    const float mu = (red[0] + red[1] + red[2] + red[3]) * (1.0f / DM);

    float d0 = x0 - mu, d1 = x1 - mu, d2 = x2 - mu, d3 = x3 - mu;
    float qq = d0*d0 + d1*d1 + d2*d2 + d3*d3;
#pragma unroll
    for (int o = 32; o > 0; o >>= 1) qq += __shfl_xor(qq, o);
    __syncthreads();
    if (lane == 0) red[wid] = qq;
    __syncthreads();
    const float var = (red[0] + red[1] + red[2] + red[3]) * (1.0f / DM);
    const float rs = rsqrtf(var + 1e-6f);

    float4 g  = ((const float4*)gamma)[tid];
    float4 be = ((const float4*)beta)[tid];
    float y0 = d0 * rs * g.x + be.x;
    float y1 = d1 * rs * g.y + be.y;
    float y2 = d2 * rs * g.z + be.z;
    float y3 = d3 * rs * g.w + be.w;

    ((float4*)(outF + row * DM))[tid] = make_float4(y0, y1, y2, y3);
    f16x4 hh; hh.x = (f16)y0; hh.y = (f16)y1; hh.z = (f16)y2; hh.w = (f16)y3;
    *(f16x4*)(outH + row * DM + tid * 4) = hh;
}

// ---------------------------------------------------------------------------
extern "C" void kernel_launch(void* const* d_in, const int* in_sizes, int n_in,
                              void* d_out, int out_size, void* d_ws, size_t ws_size,
                              hipStream_t stream)
{
    (void)in_sizes; (void)n_in; (void)d_ws; (void)ws_size; (void)out_size;
    const float* x   = (const float*)d_in[0];
    const float* enc = (const float*)d_in[1];
    const float* wq1 = (const float*)d_in[2];  const float* bq1 = (const float*)d_in[3];
    const float* wk1 = (const float*)d_in[4];  const float* bk1 = (const float*)d_in[5];
    const float* wv1 = (const float*)d_in[6];  const float* bv1 = (const float*)d_in[7];
    const float* wo1 = (const float*)d_in[8];  const float* bo1 = (const float*)d_in[9];
    const float* wq2 = (const float*)d_in[10]; const float* bq2 = (const float*)d_in[11];
    const float* wk2 = (const float*)d_in[12]; const float* bk2 = (const float*)d_in[13];
    const float* wv2 = (const float*)d_in[14]; const float* bv2 = (const float*)d_in[15];
    const float* wo2 = (const float*)d_in[16]; const float* bo2 = (const float*)d_in[17];
    const float* wf1 = (const float*)d_in[18]; const float* bf1 = (const float*)d_in[19];
    const float* wf2 = (const float*)d_in[20]; const float* bf2 = (const float*)d_in[21];
    const float* g1  = (const float*)d_in[22]; const float* be1 = (const float*)d_in[23];
    const float* g2  = (const float*)d_in[24]; const float* be2 = (const float*)d_in[25];
    const float* g3  = (const float*)d_in[26]; const float* be3 = (const float*)d_in[27];
    float* out = (float*)d_out;

    const dim3 T256(256), T32x8(32, 8);
    const long QKV_CHUNK = 8192L * 1024;

    // ---- merged convert + weight transposes ----
    cvt2_k<<<16384, T256, 0, stream>>>(x, enc);
    TWJobs jobs;
    jobs.src[0] = wq1; jobs.src[1] = wk1; jobs.src[2] = wv1; jobs.src[3] = wo1;
    jobs.src[4] = wq2; jobs.src[5] = wk2; jobs.src[6] = wv2; jobs.src[7] = wo2;
    jobs.src[8] = wf1; jobs.src[9] = wf2;
    transw_all_k<<<16384, T32x8, 0, stream>>>(jobs);

    // ---- masked self-attention ----
    // merged QKV projection; V chunk (ch=2) fused-transposed into OFF_VT
    gemm3_k<0><<<dim3(24, 64), T256, 0, stream>>>(OFF_XB, WQ1T, OFF_Q, OFF_VT,
        bq1, bk1, bv1, bv1, 1024, 1024, 1024, 1024, QKV_CHUNK, 2);
    flash_k<1><<<dim3(16, 64), T256, 0, stream>>>(OFF_Q, OFF_K, OFF_VT, OFF_AC);
    gemm3_k<2><<<dim3(8, 64), T256, 0, stream>>>(OFF_AC, WO1T, OFF_F2, 0,
        bo1, bo1, bo1, bo1, 1024, 1024, 1024, 1024, 1024, -1);
    ln_k<<<8192, T256, 0, stream>>>(OFF_F2, x, 0, g1, be1, nullptr, OFF_F1, OFF_XB);

    // ---- cross-attention (q=enc, k=enc, v=x1) ----
    gemm3_k<0><<<dim3(16, 64), T256, 0, stream>>>(OFF_ENC, WQ2T, OFF_Q, 0,
        bq2, bk2, bk2, bk2, 1024, 1024, 1024, 1024, QKV_CHUNK, -1);
    gemm3_k<0><<<dim3(8, 64), T256, 0, stream>>>(OFF_XB, WV2T, OFF_V, OFF_VT,
        bv2, bv2, bv2, bv2, 1024, 1024, 1024, 1024, 1024, 0);
    flash_k<0><<<dim3(16, 64), T256, 0, stream>>>(OFF_Q, OFF_K, OFF_VT, OFF_AC);
    gemm3_k<2><<<dim3(8, 64), T256, 0, stream>>>(OFF_AC, WO2T, OFF_F2, 0,
        bo2, bo2, bo2, bo2, 1024, 1024, 1024, 1024, 1024, -1);
    ln_k<<<8192, T256, 0, stream>>>(OFF_F2, nullptr, OFF_F1, g2, be2, nullptr, OFF_F3, OFF_XB);

    // ---- feed-forward ----
    gemm3_k<1><<<dim3(32, 64), T256, 0, stream>>>(OFF_XB, WF1T, OFF_HID, 0,
        bf1, bf1 + 1024, bf1 + 2048, bf1 + 3072, 1024, 1024, 1024, 4096, 1024, -1);
    gemm3_k<2><<<dim3(8, 64), T256, 0, stream>>>(OFF_HID, WF2T, OFF_F2, 0,
        bf2, bf2, bf2, bf2, 4096, 4096, 4096, 1024, 1024, -1);
    ln_k<<<8192, T256, 0, stream>>>(OFF_F2, nullptr, OFF_F3, g3, be3, out, 0, OFF_XB);
}

// Round 8
// 693.022 us; speedup vs baseline: 1.2402x; 1.0391x over previous
//
#include <hip/hip_runtime.h>

// ---------------------------------------------------------------------------
// Decoder layer (B=4, S=2048, D=1024, H=16, Dh=64, FF=4096), f32 in/out.
// Round 7b: flash attention v4 — single barrier per chunk, fused
// exp+cvt_pkrtz+sum (fixed builtin return type), max3 reduction tree,
// XCD-aware block swizzle, launch_bounds(256,4).
// GEMM v3 (triple-buffered, counted vmcnt) unchanged from round 6.
// ---------------------------------------------------------------------------

typedef _Float16 f16;
typedef _Float16 f16x8 __attribute__((ext_vector_type(8)));
typedef _Float16 f16x4 __attribute__((ext_vector_type(4)));
typedef __fp16 fp16x2 __attribute__((ext_vector_type(2)));
typedef float f32x4 __attribute__((ext_vector_type(4)));
typedef float f32x16 __attribute__((ext_vector_type(16)));
typedef unsigned int u32;

#define AS1 __attribute__((address_space(1)))
#define AS3 __attribute__((address_space(3)))

constexpr int S_LEN = 2048;
constexpr int DM    = 1024;

// ---- static device arena (byte offsets) ----
constexpr long OFF_W   = 0;                // transposed weights f16 (32 MiB)
constexpr long OFF_XB  = 32L  << 20;       // current stream, f16 [8192,1024]
constexpr long OFF_ENC = 48L  << 20;       // encoder f16
constexpr long OFF_Q   = 64L  << 20;
constexpr long OFF_K   = 80L  << 20;
constexpr long OFF_V   = 96L  << 20;       // scratch
constexpr long OFF_VT  = 112L << 20;       // V transposed per head [bh][64][S]
constexpr long OFF_AC  = 128L << 20;       // attention concat f16
constexpr long OFF_HID = 144L << 20;       // FF hidden f16 [8192,4096]
constexpr long OFF_F1  = 208L << 20;       // f32 [8192,1024]
constexpr long OFF_F2  = 240L << 20;       // f32
constexpr long OFF_F3  = 272L << 20;       // f32
constexpr long BUF_BYTES = 304L << 20;

__device__ alignas(4096) unsigned char g_buf[BUF_BYTES];

constexpr long WQ1T = OFF_W + (0L  << 20);
constexpr long WF1T = OFF_W + (16L << 20);  // [4096][1024]
constexpr long WF2T = OFF_W + (24L << 20);  // [1024][4096]
constexpr long WO1T = OFF_W + (6L  << 20);
constexpr long WQ2T = OFF_W + (8L  << 20);
constexpr long WV2T = OFF_W + (12L << 20);
constexpr long WO2T = OFF_W + (14L << 20);

// ---------------------------------------------------------------------------
// merged f32 -> f16 convert for x and enc (single launch)
// ---------------------------------------------------------------------------
__global__ __launch_bounds__(256) void cvt2_k(const float* __restrict__ x,
                                              const float* __restrict__ enc)
{
    const int bid = blockIdx.x;
    const bool second = bid >= 8192;
    const float* in = second ? enc : x;
    f16* out = (f16*)(g_buf + (second ? OFF_ENC : OFF_XB));
    long i = (long)(second ? bid - 8192 : bid) * 256 + threadIdx.x;
    float4 v = ((const float4*)in)[i];
    f16x4 h;
    h.x = (f16)v.x; h.y = (f16)v.y; h.z = (f16)v.z; h.w = (f16)v.w;
    *(f16x4*)(out + i * 4) = h;
}

// ---------------------------------------------------------------------------
// merged weight transpose+convert: all 10 weights in one launch.
// ---------------------------------------------------------------------------
struct TWJobs { const float* src[10]; };

__global__ __launch_bounds__(256) void transw_all_k(TWJobs jobs)
{
    __shared__ float t[32][33];
    const int bid = blockIdx.x;
    int j, local;
    if (bid < 8192)       { j = bid >> 10; local = bid & 1023; }
    else if (bid < 12288) { j = 8; local = bid - 8192; }
    else                  { j = 9; local = bid - 12288; }
    const int K = (j == 9) ? 4096 : 1024;
    const int N = (j == 8) ? 4096 : 1024;
    const int tnx = N >> 5;
    const int tx32 = local % tnx, ty32 = local / tnx;
    const long dstOff = (j < 8) ? (long)j * (2L << 20) : ((j == 8) ? WF1T : WF2T);
    const float* W = jobs.src[j];
    f16* Wt = (f16*)(g_buf + dstOff);

    int tx = threadIdx.x, ty = threadIdx.y;
    int c0 = tx32 * 32, r0 = ty32 * 32;
#pragma unroll
    for (int i = 0; i < 4; ++i)
        t[ty + 8*i][tx] = W[(long)(r0 + ty + 8*i) * N + c0 + tx];
    __syncthreads();
#pragma unroll
    for (int i = 0; i < 4; ++i)
        Wt[(long)(c0 + ty + 8*i) * K + r0 + tx] = (f16)t[tx][ty + 8*i];
}

// ---------------------------------------------------------------------------
// GEMM v3 (unchanged from round 6): BM=BN=128, BK=32, 4 waves, triple-buffered
// LDS, prefetch depth 2, counted vmcnt(4), one barrier per K-tile,
// conflict-free XOR swizzle, bijective XCD swizzle, fused V-transpose.
// ---------------------------------------------------------------------------
template<int MODE>
__global__ __launch_bounds__(256) void gemm3_k(
    long aOff, long bOff, long cOff, long vtOff,
    const float* __restrict__ b0, const float* __restrict__ b1,
    const float* __restrict__ b2, const float* __restrict__ b3,
    int K, int lda, int ldb, int ldc, long chunkStride, int tvch)
{
    __shared__ alignas(16) f16 As[3][128 * 32];
    __shared__ alignas(16) f16 Bs[3][128 * 32];

    const int tid  = threadIdx.x;
    const int lane = tid & 63;
    const int w    = tid >> 6;
    const int cB   = lane & 15;
    const int hi   = lane >> 4;

    const int nwg = gridDim.x * gridDim.y;
    const int id  = blockIdx.y * gridDim.x + blockIdx.x;
    const int swz = (id & 7) * (nwg >> 3) + (id >> 3);
    const int bx  = swz % gridDim.x, by = swz / gridDim.x;
    const int row0 = by * 128, col0 = bx * 128;

    const f16* Ab = (const f16*)(g_buf + aOff);
    const f16* Bb = (const f16*)(g_buf + bOff);

    const int wr = (w >> 1) * 64;
    const int wc = (w & 1) * 64;

    f32x4 acc[4][4] = {};

    auto stage = [&](int buf, int kt) {
        const int kB = kt * 32;
        const int base = w * 64;
#pragma unroll
        for (int r = 0; r < 2; ++r) {
            const int idx  = r * 256 + base + lane;
            const int srow = idx >> 2, sb = idx & 3;
            const int gk = (sb ^ ((srow >> 1) & 3)) << 3;
            __builtin_amdgcn_global_load_lds(
                (const AS1 void*)(Ab + (long)(row0 + srow) * lda + kB + gk),
                (AS3 void*)(&As[buf][(r * 256 + base) * 8]), 16, 0, 0);
            __builtin_amdgcn_global_load_lds(
                (const AS1 void*)(Bb + (long)(col0 + srow) * ldb + kB + gk),
                (AS3 void*)(&Bs[buf][(r * 256 + base) * 8]), 16, 0, 0);
        }
    };

    const int nt = K >> 5;
    stage(0, 0);
    stage(1, 1);

    for (int t = 0; t < nt; ++t) {
        if (nt - t >= 2) asm volatile("s_waitcnt vmcnt(4)" ::: "memory");
        else             asm volatile("s_waitcnt vmcnt(0)" ::: "memory");
        __builtin_amdgcn_s_barrier();
        __builtin_amdgcn_sched_barrier(0);
        if (t + 2 < nt) stage((t + 2) % 3, t + 2);

        const int cur = t % 3;
        f16x8 af[4], bf[4];
#pragma unroll
        for (int m = 0; m < 4; ++m) {
            const int row = wr + m * 16 + cB;
            af[m] = *(const f16x8*)&As[cur][row * 32 + ((hi ^ ((row >> 1) & 3)) << 3)];
        }
#pragma unroll
        for (int n = 0; n < 4; ++n) {
            const int row = wc + n * 16 + cB;
            bf[n] = *(const f16x8*)&Bs[cur][row * 32 + ((hi ^ ((row >> 1) & 3)) << 3)];
        }
#pragma unroll
        for (int m = 0; m < 4; ++m)
#pragma unroll
            for (int n = 0; n < 4; ++n)
                acc[m][n] = __builtin_amdgcn_mfma_f32_16x16x32_f16(af[m], bf[n], acc[m][n], 0, 0, 0);
    }

    const int ch = col0 >> 10;
    const float* bp = (ch == 0) ? b0 : (ch == 1) ? b1 : (ch == 2) ? b2 : b3;

    if (MODE == 0 && ch == tvch) {
        f16* Vt = (f16*)(g_buf + vtOff);
#pragma unroll
        for (int m = 0; m < 4; ++m) {
#pragma unroll
            for (int n = 0; n < 4; ++n) {
                const int c = col0 + wc + n * 16 + cB;
                const int hh = (c >> 6) & 15, dd = c & 63;
                const float bv = bp[c & 1023];
                const int r0e = row0 + wr + m * 16 + hi * 4;
                const int bb = r0e >> 11, sS = r0e & 2047;
                f16x4 hv;
#pragma unroll
                for (int jj = 0; jj < 4; ++jj) hv[jj] = (f16)(acc[m][n][jj] + bv);
                *(f16x4*)(Vt + (((long)(bb * 16 + hh) * 64 + dd) * 2048 + sS)) = hv;
            }
        }
        return;
    }

    float* Cf = (float*)(g_buf + cOff);
    f16*  Ch = (f16*)(g_buf + cOff);
    const long cBase = (long)ch * chunkStride;
#pragma unroll
    for (int m = 0; m < 4; ++m) {
#pragma unroll
        for (int n = 0; n < 4; ++n) {
            const int c = col0 + wc + n * 16 + cB;
            const float bv = bp[c & 1023];
#pragma unroll
            for (int jj = 0; jj < 4; ++jj) {
                const int r = row0 + wr + m * 16 + hi * 4 + jj;
                float v = acc[m][n][jj] + bv;
                if constexpr (MODE == 1) v = fmaxf(v, 0.f);
                const long idx = cBase + (long)r * ldc + (c & 1023);
                if constexpr (MODE == 2) Cf[idx] = v;
                else                     Ch[idx] = (f16)v;
            }
        }
    }
}

// ---------------------------------------------------------------------------
// Fused flash attention v4.
// Block = 128 q rows of one (b,h); 4 waves x 32 rows; KV chunk 64.
// Swapped-operand 32x32 MFMA (lane owns q-row). Single barrier per chunk
// (stage(c+1) issued a full chunk ahead of its vmcnt wait). Fused
// exp2 + cvt_pkrtz pack + sum. max3 reduction tree. Defer-rescale THR=8.
// XCD swizzle: 128 consecutive blocks per XCD, bh-major -> per-(b,h) K/V
// stays in one XCD L2.
// ---------------------------------------------------------------------------
template<int CAUSAL>
__global__ __launch_bounds__(256, 4) void flash_k(long qOff, long kOff, long vtOff, long oOff)
{
    __shared__ alignas(16) f16 KV[2][2][4096];   // [buf][K/V][64*64]

    const int tid  = threadIdx.x;
    const int lane = tid & 63;
    const int w    = tid >> 6;
    const int ql   = lane & 31;
    const int s    = lane >> 5;

    // XCD-aware swizzle: raw&7 = XCD; within an XCD blocks are bh-major.
    const int raw   = (int)blockIdx.y * (int)gridDim.x + (int)blockIdx.x;
    const int newid = (raw & 7) * 128 + (raw >> 3);
    const int bh    = newid >> 4;
    int qt = newid & 15;
    if (CAUSAL) qt = 15 - qt;                    // heavy-first per XCD

    const int b = bh >> 4, h = bh & 15;
    const int q0 = qt * 128;
    const long tokB = (long)b * S_LEN;

    const f16* Qb  = (const f16*)(g_buf + qOff);
    const f16* Kb  = (const f16*)(g_buf + kOff);
    const f16* Vtb = (const f16*)(g_buf + vtOff) + (long)bh * 64 * S_LEN;
    f16* Ob = (f16*)(g_buf + oOff);

    const int r8 = lane >> 3;
    const int c8 = lane & 7;
    const int sb = c8 ^ r8;
    const int nch = CAUSAL ? 2 * (qt + 1) : (S_LEN / 64);

    auto stage = [&](int buf, int c) {
        const int kv0s = c * 64;
#pragma unroll
        for (int t = 0; t < 2; ++t) {
            const int grp = w * 2 + t;
            const int row = grp * 8 + r8;
            __builtin_amdgcn_global_load_lds(
                (const AS1 void*)(Kb + (tokB + kv0s + row) * DM + h * 64 + sb * 8),
                (AS3 void*)(&KV[buf][0][grp * 512]), 16, 0, 0);
            __builtin_amdgcn_global_load_lds(
                (const AS1 void*)(Vtb + (long)row * S_LEN + kv0s + sb * 8),
                (AS3 void*)(&KV[buf][1][grp * 512]), 16, 0, 0);
        }
    };

    stage(0, 0);

    // Q fragments, pre-scaled by 1/sqrt(Dh) * log2(e) (softmax in exp2 dom)
    f16x8 qf[4];
    {
        const f16 hs = (f16)(0.125f * 1.44269504088896f);
        const f16* qrow = Qb + (tokB + q0 + w * 32 + ql) * DM + h * 64 + s * 8;
#pragma unroll
        for (int kk = 0; kk < 4; ++kk) {
            qf[kk] = *(const f16x8*)(qrow + kk * 16);
#pragma unroll
            for (int i = 0; i < 8; ++i) qf[kk][i] = qf[kk][i] * hs;
        }
    }

    f32x16 oacc[2] = {};
    float mrow = -1e30f, lrow = 0.f;

    for (int c = 0; c < nch; ++c) {
        const int cur = c & 1;
        const int kv0 = c * 64;

        // single barrier per chunk: own prev-chunk LDS reads done (lgkm),
        // own stage(c) landed (vmcnt); barrier makes both true block-wide.
        asm volatile("s_waitcnt vmcnt(0) lgkmcnt(0)" ::: "memory");
        __builtin_amdgcn_sched_barrier(0);
        __builtin_amdgcn_s_barrier();
        __builtin_amdgcn_sched_barrier(0);
        if (c + 1 < nch) stage(cur ^ 1, c + 1);   // overlaps compute(c)

        const bool active = !CAUSAL || (kv0 <= q0 + w * 32 + 31);
        if (active) {
            // ---- S^T = K @ Q^T ----
            f32x16 p[2] = {};
#pragma unroll
            for (int kk = 0; kk < 4; ++kk) {
                const int t16 = (kk * 2 + s) ^ (ql & 7);
                f16x8 kf0 = *(const f16x8*)((const char*)&KV[cur][0][0] + ql * 128 + t16 * 16);
                f16x8 kf1 = *(const f16x8*)((const char*)&KV[cur][0][0] + (32 + ql) * 128 + t16 * 16);
                p[0] = __builtin_amdgcn_mfma_f32_32x32x16_f16(kf0, qf[kk], p[0], 0, 0, 0);
                p[1] = __builtin_amdgcn_mfma_f32_32x32x16_f16(kf1, qf[kk], p[1], 0, 0, 0);
            }

            if (CAUSAL && (kv0 + 63 > q0 + w * 32)) {
                const int q = q0 + w * 32 + ql;
#pragma unroll
                for (int v = 0; v < 2; ++v)
#pragma unroll
                    for (int r = 0; r < 16; ++r) {
                        const int kv = kv0 + v * 32 + (r & 3) + 8 * (r >> 2) + 4 * s;
                        if (kv > q) p[v][r] = -1e30f;
                    }
            }

            // ---- row max (max3-friendly tree) ----
            float rmax = fmaxf(p[0][0], p[0][1]);
#pragma unroll
            for (int r = 2; r < 16; r += 2) rmax = fmaxf(fmaxf(p[0][r], p[0][r + 1]), rmax);
#pragma unroll
            for (int r = 0; r < 16; r += 2) rmax = fmaxf(fmaxf(p[1][r], p[1][r + 1]), rmax);
            rmax = fmaxf(rmax, __shfl_xor(rmax, 32));

            if (!__all(rmax <= mrow + 8.0f)) {       // defer-rescale (THR=8)
                const float mn = fmaxf(mrow, rmax);
                const float alpha = __builtin_amdgcn_exp2f(mrow - mn);
                lrow *= alpha;
                mrow = mn;
#pragma unroll
                for (int r = 0; r < 16; ++r) {
                    const int qr = (r & 3) + 8 * (r >> 2) + 4 * s;
                    const float ab = __shfl(alpha, qr);
                    oacc[0][r] *= ab;
                    oacc[1][r] *= ab;
                }
            }

            // ---- fused exp2 + pack(cvt_pkrtz) + sum ----
            u32 pk[2][4][2];
            float rsum = 0.f;
#pragma unroll
            for (int v = 0; v < 2; ++v)
#pragma unroll
                for (int a = 0; a < 4; ++a)
#pragma unroll
                    for (int cc = 0; cc < 2; ++cc) {
                        const float e0 = __builtin_amdgcn_exp2f(p[v][4 * a + 2 * cc] - mrow);
                        const float e1 = __builtin_amdgcn_exp2f(p[v][4 * a + 2 * cc + 1] - mrow);
                        rsum += e0 + e1;
                        union { fp16x2 h; u32 u; } cv;
                        cv.h = __builtin_amdgcn_cvt_pkrtz(e0, e1);
                        pk[v][a][cc] = cv.u;
                    }
            rsum += __shfl_xor(rsum, 32);
            lrow += rsum;

            // ---- half exchange for PV A-fragments ----
            u32 loc[2][2][2], exv[2][2][2];
#pragma unroll
            for (int v = 0; v < 2; ++v)
#pragma unroll
                for (int k1 = 0; k1 < 2; ++k1)
#pragma unroll
                    for (int cc = 0; cc < 2; ++cc) {
                        const u32 pe = pk[v][2 * k1][cc];
                        const u32 po = pk[v][2 * k1 + 1][cc];
                        loc[v][k1][cc] = s ? po : pe;
                        const u32 snd = s ? pe : po;
                        exv[v][k1][cc] = (u32)__shfl_xor((int)snd, 32);
                    }

            // ---- O += P @ V ----
#pragma unroll
            for (int ks = 0; ks < 4; ++ks) {
                const int v = ks >> 1, k1 = ks & 1;
                union { u32 u[4]; f16x8 hv; } pa;
                pa.u[0] = s ? exv[v][k1][0] : loc[v][k1][0];
                pa.u[1] = s ? exv[v][k1][1] : loc[v][k1][1];
                pa.u[2] = s ? loc[v][k1][0] : exv[v][k1][0];
                pa.u[3] = s ? loc[v][k1][1] : exv[v][k1][1];
                const int tv = (ks * 2 + s) ^ (ql & 7);
                f16x8 vf0 = *(const f16x8*)((const char*)&KV[cur][1][0] + ql * 128 + tv * 16);
                f16x8 vf1 = *(const f16x8*)((const char*)&KV[cur][1][0] + (32 + ql) * 128 + tv * 16);
                oacc[0] = __builtin_amdgcn_mfma_f32_32x32x16_f16(pa.hv, vf0, oacc[0], 0, 0, 0);
                oacc[1] = __builtin_amdgcn_mfma_f32_32x32x16_f16(pa.hv, vf1, oacc[1], 0, 0, 0);
            }
        }
    }

    // all waves must finish their last-chunk LDS reads before Es overwrites KV
    asm volatile("s_waitcnt lgkmcnt(0)" ::: "memory");
    __builtin_amdgcn_sched_barrier(0);
    __builtin_amdgcn_s_barrier();

    // ---- epilogue: normalize, transpose via LDS, coalesced store ----
    f16* Es = ((f16*)&KV[0][0][0]) + w * 2304;
    const float linv = 1.0f / lrow;
#pragma unroll
    for (int r = 0; r < 16; ++r) {
        const int qr = (r & 3) + 8 * (r >> 2) + 4 * s;
        const float lb = __shfl(linv, qr);
        Es[qr * 72 + ql]      = (f16)(oacc[0][r] * lb);
        Es[qr * 72 + 32 + ql] = (f16)(oacc[1][r] * lb);
    }
    const int orow = lane >> 1;
    const int oh   = (lane & 1) * 32;
    const f16* srcp = ((const f16*)&KV[0][0][0]) + w * 2304 + orow * 72 + oh;
    f16* dst = Ob + (tokB + q0 + w * 32 + orow) * DM + h * 64 + oh;
#pragma unroll
    for (int t = 0; t < 4; ++t)
        *(f16x8*)(dst + t * 8) = *(const f16x8*)(srcp + t * 8);
}

// ---------------------------------------------------------------------------
// fused residual-add + LayerNorm
// ---------------------------------------------------------------------------
__global__ __launch_bounds__(256) void ln_k(
    long inOff, const float* __restrict__ residExt, long residOff,
    const float* __restrict__ gamma, const float* __restrict__ beta,
    float* __restrict__ outFExt, long outFOff, long outHOff)
{
    const float* in    = (const float*)(g_buf + inOff);
    const float* resid = residExt ? residExt : (const float*)(g_buf + residOff);
    float* outF = outFExt ? outFExt : (float*)(g_buf + outFOff);
    f16*  outH = (f16*)(g_buf + outHOff);

    const long row = blockIdx.x;
    const int tid = threadIdx.x;
    const int lane = tid & 63, wid = tid >> 6;

    float4 a  = ((const float4*)(in    + row * DM))[tid];
    float4 rr = ((const float4*)(resid + row * DM))[tid];
    float x0 = a.x + rr.x, x1 = a.y + rr.y, x2 = a.z + rr.z, x3 = a.w + rr.w;

    __shared__ float red[4];
    float ss = x0 + x1 + x2 + x3;
#pragma unroll
    for (int o = 32; o > 0; o >>= 1) ss += __shfl_xor(ss, o);
    if (lane == 0) red[wid] = ss;
    __syncthreads();
    const float mu = (red[0] + red[1] + red[2] + red[3]) * (1.0f / DM);

    float d0 = x0 - mu, d1 = x1 - mu, d2 = x2 - mu, d3 = x3 - mu;
    float qq = d0*d0 + d1*d1 + d2*d2 + d3*d3;
#pragma unroll
    for (int o = 32; o > 0; o >>= 1) qq += __shfl_xor(qq, o);
    __syncthreads();
    if (lane == 0) red[wid] = qq;
    __syncthreads();
    const float var = (red[0] + red[1] + red[2] + red[3]) * (1.0f / DM);
    const float rs = rsqrtf(var + 1e-6f);

    float4 g  = ((const float4*)gamma)[tid];
    float4 be = ((const float4*)beta)[tid];
    float y0 = d0 * rs * g.x + be.x;
    float y1 = d1 * rs * g.y + be.y;
    float y2 = d2 * rs * g.z + be.z;
    float y3 = d3 * rs * g.w + be.w;

    ((float4*)(outF + row * DM))[tid] = make_float4(y0, y1, y2, y3);
    f16x4 hh; hh.x = (f16)y0; hh.y = (f16)y1; hh.z = (f16)y2; hh.w = (f16)y3;
    *(f16x4*)(outH + row * DM + tid * 4) = hh;
}

// ---------------------------------------------------------------------------
extern "C" void kernel_launch(void* const* d_in, const int* in_sizes, int n_in,
                              void* d_out, int out_size, void* d_ws, size_t ws_size,
                              hipStream_t stream)
{
    (void)in_sizes; (void)n_in; (void)d_ws; (void)ws_size; (void)out_size;
    const float* x   = (const float*)d_in[0];
    const float* enc = (const float*)d_in[1];
    const float* wq1 = (const float*)d_in[2];  const float* bq1 = (const float*)d_in[3];
    const float* wk1 = (const float*)d_in[4];  const float* bk1 = (const float*)d_in[5];
    const float* wv1 = (const float*)d_in[6];  const float* bv1 = (const float*)d_in[7];
    const float* wo1 = (const float*)d_in[8];  const float* bo1 = (const float*)d_in[9];
    const float* wq2 = (const float*)d_in[10]; const float* bq2 = (const float*)d_in[11];
    const float* wk2 = (const float*)d_in[12]; const float* bk2 = (const float*)d_in[13];
    const float* wv2 = (const float*)d_in[14]; const float* bv2 = (const float*)d_in[15];
    const float* wo2 = (const float*)d_in[16]; const float* bo2 = (const float*)d_in[17];
    const float* wf1 = (const float*)d_in[18]; const float* bf1 = (const float*)d_in[19];
    const float* wf2 = (const float*)d_in[20]; const float* bf2 = (const float*)d_in[21];
    const float* g1  = (const float*)d_in[22]; const float* be1 = (const float*)d_in[23];
    const float* g2  = (const float*)d_in[24]; const float* be2 = (const float*)d_in[25];
    const float* g3  = (const float*)d_in[26]; const float* be3 = (const float*)d_in[27];
    float* out = (float*)d_out;

    const dim3 T256(256), T32x8(32, 8);
    const long QKV_CHUNK = 8192L * 1024;

    // ---- merged convert + weight transposes ----
    cvt2_k<<<16384, T256, 0, stream>>>(x, enc);
    TWJobs jobs;
    jobs.src[0] = wq1; jobs.src[1] = wk1; jobs.src[2] = wv1; jobs.src[3] = wo1;
    jobs.src[4] = wq2; jobs.src[5] = wk2; jobs.src[6] = wv2; jobs.src[7] = wo2;
    jobs.src[8] = wf1; jobs.src[9] = wf2;
    transw_all_k<<<16384, T32x8, 0, stream>>>(jobs);

    // ---- masked self-attention ----
    gemm3_k<0><<<dim3(24, 64), T256, 0, stream>>>(OFF_XB, WQ1T, OFF_Q, OFF_VT,
        bq1, bk1, bv1, bv1, 1024, 1024, 1024, 1024, QKV_CHUNK, 2);
    flash_k<1><<<dim3(16, 64), T256, 0, stream>>>(OFF_Q, OFF_K, OFF_VT, OFF_AC);
    gemm3_k<2><<<dim3(8, 64), T256, 0, stream>>>(OFF_AC, WO1T, OFF_F2, 0,
        bo1, bo1, bo1, bo1, 1024, 1024, 1024, 1024, 1024, -1);
    ln_k<<<8192, T256, 0, stream>>>(OFF_F2, x, 0, g1, be1, nullptr, OFF_F1, OFF_XB);

    // ---- cross-attention (q=enc, k=enc, v=x1) ----
    gemm3_k<0><<<dim3(16, 64), T256, 0, stream>>>(OFF_ENC, WQ2T, OFF_Q, 0,
        bq2, bk2, bk2, bk2, 1024, 1024, 1024, 1024, QKV_CHUNK, -1);
    gemm3_k<0><<<dim3(8, 64), T256, 0, stream>>>(OFF_XB, WV2T, OFF_V, OFF_VT,
        bv2, bv2, bv2, bv2, 1024, 1024, 1024, 1024, 1024, 0);
    flash_k<0><<<dim3(16, 64), T256, 0, stream>>>(OFF_Q, OFF_K, OFF_VT, OFF_AC);
    gemm3_k<2><<<dim3(8, 64), T256, 0, stream>>>(OFF_AC, WO2T, OFF_F2, 0,
        bo2, bo2, bo2, bo2, 1024, 1024, 1024, 1024, 1024, -1);
    ln_k<<<8192, T256, 0, stream>>>(OFF_F2, nullptr, OFF_F1, g2, be2, nullptr, OFF_F3, OFF_XB);

    // ---- feed-forward ----
    gemm3_k<1><<<dim3(32, 64), T256, 0, stream>>>(OFF_XB, WF1T, OFF_HID, 0,
        bf1, bf1 + 1024, bf1 + 2048, bf1 + 3072, 1024, 1024, 1024, 4096, 1024, -1);
    gemm3_k<2><<<dim3(8, 64), T256, 0, stream>>>(OFF_HID, WF2T, OFF_F2, 0,
        bf2, bf2, bf2, bf2, 4096, 4096, 4096, 1024, 1024, -1);
    ln_k<<<8192, T256, 0, stream>>>(OFF_F2, nullptr, OFF_F3, g3, be3, out, 0, OFF_XB);
}